// Round 3
// baseline (430.217 us; speedup 1.0000x reference)
//
#include <hip/hip_runtime.h>

// PerformerAttention: B=4 H=16 S=4096 D=64, fp32.
//   q = relu(Q)+eps; k = (relu(K)+eps)*mask
//   kv[bh][d][e] = sum_s k[s][d]*v[s][e];  ksum[bh][d] = sum_s k[s][d]
//   out[s][e] = (sum_d q[s][d]*kv[d][e]) / (sum_d q[s][d]*ksum[d])
//
// R3: pass-1 occupancy fix. CH1=16 -> 1024 blocks (4/CU, 16 waves/CU) and
// block-level LDS combine of the 4 wave partials -> 1 segment per block
// (partial traffic 33->17 MB). Pass 2 unchanged (need clean counters).

namespace {
constexpr int kB = 4, kH = 16, kS = 4096, kD = 64;
constexpr int kBH = kB * kH;
constexpr float kEps = 0.001f;

constexpr int KVSZ = kD * kD;     // 4096 floats
constexpr int SEG  = KVSZ + kD;   // 4160 floats per partial segment (kv + ksum)
constexpr int F4PS = SEG / 4;     // 1040 float4 per segment
}

// ---------------- Pass 1: partial kv + ksum, one segment per BLOCK ---------
__global__ __launch_bounds__(256, 4)
void pa_kv_partial(const float* __restrict__ key, const float* __restrict__ value,
                   const float* __restrict__ mask, float* __restrict__ P, int ch1) {
  __shared__ float smem[4096];   // 4 waves x (ks 512 + vs 512); reused for combine
  __shared__ float ksm[256];     // per-wave ksum staging

  const int tid  = threadIdx.x;
  const int wid  = tid >> 6;
  const int lane = tid & 63;

  const int bh    = blockIdx.x / ch1;
  const int chunk = blockIdx.x - bh * ch1;
  const int b     = bh >> 4;                 // kH = 16
  const int rows  = kS / ch1;
  const int s0    = chunk * rows;
  const int tiles = rows >> 5;               // 8-row tiles, strided by 4 waves

  const float* kb = key   + (size_t)bh * kS * kD;
  const float* vb = value + (size_t)bh * kS * kD;
  const float* mb = mask  + (size_t)b * kS;

  float* ksT = smem + wid * 1024;            // 8 x 64 (wave-private)
  float* vsT = smem + wid * 1024 + 512;      // 8 x 64

  const int lrow = lane >> 4;                // 0..3   (load map)
  const int lcol = (lane & 15) << 2;         // 0..60
  const int ti   = lane >> 3;                // 0..7   (compute map: d rows 8*ti..)
  const int tj   = lane & 7;                 // 0..7   (e cols 8*tj..)

  float acc[8][8];
#pragma unroll
  for (int i = 0; i < 8; ++i)
#pragma unroll
    for (int j = 0; j < 8; ++j) acc[i][j] = 0.f;
  float4 ksacc = make_float4(0.f, 0.f, 0.f, 0.f);

  // prefetch tile 0 for this wave
  int ts = s0 + wid * 8;
  float4 kq0 = *(const float4*)(kb + (size_t)(ts + lrow) * kD + lcol);
  float4 kq1 = *(const float4*)(kb + (size_t)(ts + 4 + lrow) * kD + lcol);
  float4 vq0 = *(const float4*)(vb + (size_t)(ts + lrow) * kD + lcol);
  float4 vq1 = *(const float4*)(vb + (size_t)(ts + 4 + lrow) * kD + lcol);
  float  m0  = mb[ts + lrow];
  float  m1  = mb[ts + 4 + lrow];

  for (int t = 0; t < tiles; ++t) {
    float4 kt0, kt1;
    kt0.x = (fmaxf(kq0.x, 0.f) + kEps) * m0;
    kt0.y = (fmaxf(kq0.y, 0.f) + kEps) * m0;
    kt0.z = (fmaxf(kq0.z, 0.f) + kEps) * m0;
    kt0.w = (fmaxf(kq0.w, 0.f) + kEps) * m0;
    kt1.x = (fmaxf(kq1.x, 0.f) + kEps) * m1;
    kt1.y = (fmaxf(kq1.y, 0.f) + kEps) * m1;
    kt1.z = (fmaxf(kq1.z, 0.f) + kEps) * m1;
    kt1.w = (fmaxf(kq1.w, 0.f) + kEps) * m1;

    ksacc.x += kt0.x + kt1.x;
    ksacc.y += kt0.y + kt1.y;
    ksacc.z += kt0.z + kt1.z;
    ksacc.w += kt0.w + kt1.w;

    // wave-private LDS tile: no block barrier (in-order DS, lockstep wave)
    *(float4*)&ksT[lrow * 64 + lcol]       = kt0;
    *(float4*)&ksT[(lrow + 4) * 64 + lcol] = kt1;
    *(float4*)&vsT[lrow * 64 + lcol]       = vq0;
    *(float4*)&vsT[(lrow + 4) * 64 + lcol] = vq1;

    if (t + 1 < tiles) {                    // register prefetch of next tile
      ts += 32;                             // 4 waves x 8 rows
      kq0 = *(const float4*)(kb + (size_t)(ts + lrow) * kD + lcol);
      kq1 = *(const float4*)(kb + (size_t)(ts + 4 + lrow) * kD + lcol);
      vq0 = *(const float4*)(vb + (size_t)(ts + lrow) * kD + lcol);
      vq1 = *(const float4*)(vb + (size_t)(ts + 4 + lrow) * kD + lcol);
      m0  = mb[ts + lrow];
      m1  = mb[ts + 4 + lrow];
    }

#pragma unroll
    for (int ss = 0; ss < 8; ++ss) {
      const float4 kf0 = *(const float4*)&ksT[ss * 64 + 8 * ti];
      const float4 kf1 = *(const float4*)&ksT[ss * 64 + 8 * ti + 4];
      const float4 vf0 = *(const float4*)&vsT[ss * 64 + 8 * tj];
      const float4 vf1 = *(const float4*)&vsT[ss * 64 + 8 * tj + 4];
      const float ka[8] = {kf0.x, kf0.y, kf0.z, kf0.w, kf1.x, kf1.y, kf1.z, kf1.w};
      const float va[8] = {vf0.x, vf0.y, vf0.z, vf0.w, vf1.x, vf1.y, vf1.z, vf1.w};
#pragma unroll
      for (int i = 0; i < 8; ++i)
#pragma unroll
        for (int j = 0; j < 8; ++j) acc[i][j] = fmaf(ka[i], va[j], acc[i][j]);
    }
  }

  // per-wave ksum fold: lanes sharing (lane&15) hold disjoint row partials
  ksacc.x += __shfl_xor(ksacc.x, 16); ksacc.x += __shfl_xor(ksacc.x, 32);
  ksacc.y += __shfl_xor(ksacc.y, 16); ksacc.y += __shfl_xor(ksacc.y, 32);
  ksacc.z += __shfl_xor(ksacc.z, 16); ksacc.z += __shfl_xor(ksacc.z, 32);
  ksacc.w += __shfl_xor(ksacc.w, 16); ksacc.w += __shfl_xor(ksacc.w, 32);
  if (lane < 16) *(float4*)&ksm[wid * 64 + 4 * lane] = ksacc;

  // block combine: wave w adds its 8x8 acc into smem[4096] (permuted layout:
  // f4 slot j*64+lane = kv[8*(lane>>3)+(j>>1)][8*(lane&7)+4*(j&1)..])
#pragma unroll
  for (int w = 0; w < 4; ++w) {
    __syncthreads();
    if (wid == w) {
#pragma unroll
      for (int i = 0; i < 8; ++i)
#pragma unroll
        for (int jj = 0; jj < 2; ++jj) {
          const int j = i * 2 + jj;
          float4 o = make_float4(acc[i][jj * 4 + 0], acc[i][jj * 4 + 1],
                                 acc[i][jj * 4 + 2], acc[i][jj * 4 + 3]);
          float* p = &smem[(size_t)(j * 64 + lane) * 4];
          if (w != 0) {
            const float4 prev = *(const float4*)p;
            o.x += prev.x; o.y += prev.y; o.z += prev.z; o.w += prev.w;
          }
          *(float4*)p = o;
        }
    }
  }
  __syncthreads();

  // cooperative coalesced store of the single block segment
  float* Pd = P + (size_t)blockIdx.x * SEG;
#pragma unroll
  for (int i = 0; i < 4; ++i) {
    const int idx = tid + 256 * i;
    *(float4*)&Pd[(size_t)idx * 4] = *(const float4*)&smem[(size_t)idx * 4];
  }
  if (tid < kD)
    Pd[KVSZ + tid] = ksm[tid] + ksm[64 + tid] + ksm[128 + tid] + ksm[192 + tid];
}

// ---------------- Reduce: sum block partials, un-permute kv ----------------
__global__ __launch_bounds__(256)
void pa_reduce(const float* __restrict__ P, float* __restrict__ R, int nseg) {
  const int gid = blockIdx.x * 256 + threadIdx.x;
  if (gid >= kBH * F4PS) return;
  const int bh  = gid / F4PS;
  const int pos = gid - bh * F4PS;

  const float* base = P + (size_t)bh * nseg * SEG + (size_t)pos * 4;
  float ax = 0.f, ay = 0.f, az = 0.f, aw = 0.f;
  for (int c = 0; c < nseg; ++c) {
    const float4 t = *(const float4*)(base + (size_t)c * SEG);
    ax += t.x; ay += t.y; az += t.z; aw += t.w;
  }

  int dpos;
  if (pos < KVSZ / 4) {          // un-permute to natural [d][e]
    const int j  = pos >> 6, ln = pos & 63;
    const int d  = 8 * (ln >> 3) + (j >> 1);
    const int e4 = 2 * (ln & 7) + (j & 1);
    dpos = d * 16 + e4;
  } else {
    dpos = pos;                  // ksum already natural
  }
  *(float4*)&R[(size_t)bh * SEG + (size_t)dpos * 4] = make_float4(ax, ay, az, aw);
}

// ---------------- Pass 2: out = (q . kv) / (q . ksum) ----------------------
__global__ __launch_bounds__(256)
void pa_out(const float* __restrict__ query, const float* __restrict__ R,
            float* __restrict__ out) {
  __shared__ float ost[64 * 68];   // 64-row output staging, pad 68 (17 KiB)

  const int tid    = threadIdx.x;
  const int bh     = blockIdx.x >> 4;
  const int rowblk = blockIdx.x & 15;
  const int s      = rowblk * 256 + tid;

  const float* qrow = query + ((size_t)bh * kS + s) * kD;
  const float* Rb   = R + (size_t)bh * SEG;   // wave-uniform -> scalar loads

  float4 acc[16];
#pragma unroll
  for (int e = 0; e < 16; ++e) acc[e] = make_float4(0.f, 0.f, 0.f, 0.f);
  float den = 0.f;

#pragma unroll 4
  for (int d4 = 0; d4 < 16; ++d4) {
    const float4 qv = *(const float4*)(qrow + 4 * d4);
    const float qd[4] = {fmaxf(qv.x, 0.f) + kEps, fmaxf(qv.y, 0.f) + kEps,
                         fmaxf(qv.z, 0.f) + kEps, fmaxf(qv.w, 0.f) + kEps};
#pragma unroll
    for (int dd = 0; dd < 4; ++dd) {
      const int d = 4 * d4 + dd;
      den = fmaf(qd[dd], Rb[KVSZ + d], den);
      const float* kvr = Rb + d * 64;          // uniform row -> SGPR broadcast
#pragma unroll
      for (int e = 0; e < 16; ++e) {
        acc[e].x = fmaf(qd[dd], kvr[4 * e + 0], acc[e].x);
        acc[e].y = fmaf(qd[dd], kvr[4 * e + 1], acc[e].y);
        acc[e].z = fmaf(qd[dd], kvr[4 * e + 2], acc[e].z);
        acc[e].w = fmaf(qd[dd], kvr[4 * e + 3], acc[e].w);
      }
    }
  }

  const float inv = 1.0f / den;
#pragma unroll
  for (int e = 0; e < 16; ++e) {
    acc[e].x *= inv; acc[e].y *= inv; acc[e].z *= inv; acc[e].w *= inv;
  }

  // staged coalesced store: batch bb covers 64 rows written by wave bb
  float* ob = out + ((size_t)bh * kS + (size_t)rowblk * 256) * kD;
  const int wid = tid >> 6, l = tid & 63;
  for (int bb = 0; bb < 4; ++bb) {
    if (wid == bb) {
#pragma unroll
      for (int e = 0; e < 16; ++e) *(float4*)&ost[l * 68 + 4 * e] = acc[e];
    }
    __syncthreads();
#pragma unroll
    for (int jj = 0; jj < 4; ++jj) {
      const int g = tid + 256 * jj;
      const int r = g >> 4, c = g & 15;
      *(float4*)&ob[(size_t)(bb * 64 + r) * kD + 4 * c] =
          *(const float4*)&ost[r * 68 + 4 * c];
    }
    __syncthreads();
  }
}

extern "C" void kernel_launch(void* const* d_in, const int* in_sizes, int n_in,
                              void* d_out, int out_size, void* d_ws, size_t ws_size,
                              hipStream_t stream) {
  const float* query = (const float*)d_in[0];
  const float* key   = (const float*)d_in[1];
  const float* value = (const float*)d_in[2];
  const float* mask  = (const float*)d_in[3];
  float* outp = (float*)d_out;

  // CH1 = S-chunks per bh; ONE segment per block now. Pick largest that fits.
  auto need = [](int ch1) -> size_t {
    return (size_t)(kBH * ch1 + kBH) * SEG * sizeof(float);
  };
  int CH1 = 8;                                  // 9.2 MB, known-safe floor
  if (ws_size >= need(16)) CH1 = 16;            // 18.1 MB, 1024 blocks (4/CU)

  float* P = (float*)d_ws;                      // kBH*CH1 segments
  float* R = P + (size_t)kBH * CH1 * SEG;       // kBH segments (natural layout)

  hipLaunchKernelGGL(pa_kv_partial, dim3(kBH * CH1), dim3(256), 0, stream,
                     key, value, mask, P, CH1);
  hipLaunchKernelGGL(pa_reduce, dim3((kBH * F4PS + 255) / 256), dim3(256), 0, stream,
                     P, R, CH1);
  hipLaunchKernelGGL(pa_out, dim3(kBH * 16), dim3(256), 0, stream,
                     query, R, outp);
}

// Round 4
// 249.426 us; speedup vs baseline: 1.7248x; 1.7248x over previous
//
#include <hip/hip_runtime.h>

// PerformerAttention: B=4 H=16 S=4096 D=64, fp32.
//   q = relu(Q)+eps; k = (relu(K)+eps)*mask
//   kv[bh][d][e] = sum_s k[s][d]*v[s][e];  ksum[bh][d] = sum_s k[s][d]
//   out[s][e] = (sum_d q[s][d]*kv[d][e]) / (sum_d q[s][d]*ksum[d])
//
// R4: revert the __launch_bounds__(256,4) register cap that forced VGPR
// 108->64 and spilled acc[8][8] to scratch (FETCH/WRITE 286/482 MB, 245 us).
// Keep (256,2) as in the 62-us R2 build (VGPR 108 already permits 4 waves/EU
// at runtime). Keep CH1=16 grid (1024 blocks = 4/CU) + block-level combine.

namespace {
constexpr int kB = 4, kH = 16, kS = 4096, kD = 64;
constexpr int kBH = kB * kH;
constexpr float kEps = 0.001f;

constexpr int KVSZ = kD * kD;     // 4096 floats
constexpr int SEG  = KVSZ + kD;   // 4160 floats per partial segment (kv + ksum)
constexpr int F4PS = SEG / 4;     // 1040 float4 per segment
}

// ---------------- Pass 1: partial kv + ksum, one segment per BLOCK ---------
__global__ __launch_bounds__(256, 2)   // (256,4) caused a 64-VGPR spill disaster; do not re-add
void pa_kv_partial(const float* __restrict__ key, const float* __restrict__ value,
                   const float* __restrict__ mask, float* __restrict__ P, int ch1) {
  __shared__ float smem[4096];   // 4 waves x (ks 512 + vs 512); reused for combine
  __shared__ float ksm[256];     // per-wave ksum staging

  const int tid  = threadIdx.x;
  const int wid  = tid >> 6;
  const int lane = tid & 63;

  const int bh    = blockIdx.x / ch1;
  const int chunk = blockIdx.x - bh * ch1;
  const int b     = bh >> 4;                 // kH = 16
  const int rows  = kS / ch1;
  const int s0    = chunk * rows;
  const int tiles = rows >> 5;               // 8-row tiles, strided by 4 waves

  const float* kb = key   + (size_t)bh * kS * kD;
  const float* vb = value + (size_t)bh * kS * kD;
  const float* mb = mask  + (size_t)b * kS;

  float* ksT = smem + wid * 1024;            // 8 x 64 (wave-private)
  float* vsT = smem + wid * 1024 + 512;      // 8 x 64

  const int lrow = lane >> 4;                // 0..3   (load map)
  const int lcol = (lane & 15) << 2;         // 0..60
  const int ti   = lane >> 3;                // 0..7   (compute map: d rows 8*ti..)
  const int tj   = lane & 7;                 // 0..7   (e cols 8*tj..)

  float acc[8][8];
#pragma unroll
  for (int i = 0; i < 8; ++i)
#pragma unroll
    for (int j = 0; j < 8; ++j) acc[i][j] = 0.f;
  float4 ksacc = make_float4(0.f, 0.f, 0.f, 0.f);

  // prefetch tile 0 for this wave
  int ts = s0 + wid * 8;
  float4 kq0 = *(const float4*)(kb + (size_t)(ts + lrow) * kD + lcol);
  float4 kq1 = *(const float4*)(kb + (size_t)(ts + 4 + lrow) * kD + lcol);
  float4 vq0 = *(const float4*)(vb + (size_t)(ts + lrow) * kD + lcol);
  float4 vq1 = *(const float4*)(vb + (size_t)(ts + 4 + lrow) * kD + lcol);
  float  m0  = mb[ts + lrow];
  float  m1  = mb[ts + 4 + lrow];

  for (int t = 0; t < tiles; ++t) {
    float4 kt0, kt1;
    kt0.x = (fmaxf(kq0.x, 0.f) + kEps) * m0;
    kt0.y = (fmaxf(kq0.y, 0.f) + kEps) * m0;
    kt0.z = (fmaxf(kq0.z, 0.f) + kEps) * m0;
    kt0.w = (fmaxf(kq0.w, 0.f) + kEps) * m0;
    kt1.x = (fmaxf(kq1.x, 0.f) + kEps) * m1;
    kt1.y = (fmaxf(kq1.y, 0.f) + kEps) * m1;
    kt1.z = (fmaxf(kq1.z, 0.f) + kEps) * m1;
    kt1.w = (fmaxf(kq1.w, 0.f) + kEps) * m1;

    ksacc.x += kt0.x + kt1.x;
    ksacc.y += kt0.y + kt1.y;
    ksacc.z += kt0.z + kt1.z;
    ksacc.w += kt0.w + kt1.w;

    // wave-private LDS tile: no block barrier (in-order DS, lockstep wave)
    *(float4*)&ksT[lrow * 64 + lcol]       = kt0;
    *(float4*)&ksT[(lrow + 4) * 64 + lcol] = kt1;
    *(float4*)&vsT[lrow * 64 + lcol]       = vq0;
    *(float4*)&vsT[(lrow + 4) * 64 + lcol] = vq1;

    if (t + 1 < tiles) {                    // register prefetch of next tile
      ts += 32;                             // 4 waves x 8 rows
      kq0 = *(const float4*)(kb + (size_t)(ts + lrow) * kD + lcol);
      kq1 = *(const float4*)(kb + (size_t)(ts + 4 + lrow) * kD + lcol);
      vq0 = *(const float4*)(vb + (size_t)(ts + lrow) * kD + lcol);
      vq1 = *(const float4*)(vb + (size_t)(ts + 4 + lrow) * kD + lcol);
      m0  = mb[ts + lrow];
      m1  = mb[ts + 4 + lrow];
    }

#pragma unroll
    for (int ss = 0; ss < 8; ++ss) {
      const float4 kf0 = *(const float4*)&ksT[ss * 64 + 8 * ti];
      const float4 kf1 = *(const float4*)&ksT[ss * 64 + 8 * ti + 4];
      const float4 vf0 = *(const float4*)&vsT[ss * 64 + 8 * tj];
      const float4 vf1 = *(const float4*)&vsT[ss * 64 + 8 * tj + 4];
      const float ka[8] = {kf0.x, kf0.y, kf0.z, kf0.w, kf1.x, kf1.y, kf1.z, kf1.w};
      const float va[8] = {vf0.x, vf0.y, vf0.z, vf0.w, vf1.x, vf1.y, vf1.z, vf1.w};
#pragma unroll
      for (int i = 0; i < 8; ++i)
#pragma unroll
        for (int j = 0; j < 8; ++j) acc[i][j] = fmaf(ka[i], va[j], acc[i][j]);
    }
  }

  // per-wave ksum fold: lanes sharing (lane&15) hold disjoint row partials
  ksacc.x += __shfl_xor(ksacc.x, 16); ksacc.x += __shfl_xor(ksacc.x, 32);
  ksacc.y += __shfl_xor(ksacc.y, 16); ksacc.y += __shfl_xor(ksacc.y, 32);
  ksacc.z += __shfl_xor(ksacc.z, 16); ksacc.z += __shfl_xor(ksacc.z, 32);
  ksacc.w += __shfl_xor(ksacc.w, 16); ksacc.w += __shfl_xor(ksacc.w, 32);
  if (lane < 16) *(float4*)&ksm[wid * 64 + 4 * lane] = ksacc;

  // block combine: wave w adds its 8x8 acc into smem[4096] (permuted layout:
  // f4 slot j*64+lane = kv[8*(lane>>3)+(j>>1)][8*(lane&7)+4*(j&1)..])
#pragma unroll
  for (int w = 0; w < 4; ++w) {
    __syncthreads();
    if (wid == w) {
#pragma unroll
      for (int i = 0; i < 8; ++i)
#pragma unroll
        for (int jj = 0; jj < 2; ++jj) {
          const int j = i * 2 + jj;
          float4 o = make_float4(acc[i][jj * 4 + 0], acc[i][jj * 4 + 1],
                                 acc[i][jj * 4 + 2], acc[i][jj * 4 + 3]);
          float* p = &smem[(size_t)(j * 64 + lane) * 4];
          if (w != 0) {
            const float4 prev = *(const float4*)p;
            o.x += prev.x; o.y += prev.y; o.z += prev.z; o.w += prev.w;
          }
          *(float4*)p = o;
        }
    }
  }
  __syncthreads();

  // cooperative coalesced store of the single block segment
  float* Pd = P + (size_t)blockIdx.x * SEG;
#pragma unroll
  for (int i = 0; i < 4; ++i) {
    const int idx = tid + 256 * i;
    *(float4*)&Pd[(size_t)idx * 4] = *(const float4*)&smem[(size_t)idx * 4];
  }
  if (tid < kD)
    Pd[KVSZ + tid] = ksm[tid] + ksm[64 + tid] + ksm[128 + tid] + ksm[192 + tid];
}

// ---------------- Reduce: sum block partials, un-permute kv ----------------
__global__ __launch_bounds__(256)
void pa_reduce(const float* __restrict__ P, float* __restrict__ R, int nseg) {
  const int gid = blockIdx.x * 256 + threadIdx.x;
  if (gid >= kBH * F4PS) return;
  const int bh  = gid / F4PS;
  const int pos = gid - bh * F4PS;

  const float* base = P + (size_t)bh * nseg * SEG + (size_t)pos * 4;
  float ax = 0.f, ay = 0.f, az = 0.f, aw = 0.f;
  for (int c = 0; c < nseg; ++c) {
    const float4 t = *(const float4*)(base + (size_t)c * SEG);
    ax += t.x; ay += t.y; az += t.z; aw += t.w;
  }

  int dpos;
  if (pos < KVSZ / 4) {          // un-permute to natural [d][e]
    const int j  = pos >> 6, ln = pos & 63;
    const int d  = 8 * (ln >> 3) + (j >> 1);
    const int e4 = 2 * (ln & 7) + (j & 1);
    dpos = d * 16 + e4;
  } else {
    dpos = pos;                  // ksum already natural
  }
  *(float4*)&R[(size_t)bh * SEG + (size_t)dpos * 4] = make_float4(ax, ay, az, aw);
}

// ---------------- Pass 2: out = (q . kv) / (q . ksum) ----------------------
__global__ __launch_bounds__(256)
void pa_out(const float* __restrict__ query, const float* __restrict__ R,
            float* __restrict__ out) {
  __shared__ float ost[64 * 68];   // 64-row output staging, pad 68 (17 KiB)

  const int tid    = threadIdx.x;
  const int bh     = blockIdx.x >> 4;
  const int rowblk = blockIdx.x & 15;
  const int s      = rowblk * 256 + tid;

  const float* qrow = query + ((size_t)bh * kS + s) * kD;
  const float* Rb   = R + (size_t)bh * SEG;   // wave-uniform -> scalar loads

  float4 acc[16];
#pragma unroll
  for (int e = 0; e < 16; ++e) acc[e] = make_float4(0.f, 0.f, 0.f, 0.f);
  float den = 0.f;

#pragma unroll 4
  for (int d4 = 0; d4 < 16; ++d4) {
    const float4 qv = *(const float4*)(qrow + 4 * d4);
    const float qd[4] = {fmaxf(qv.x, 0.f) + kEps, fmaxf(qv.y, 0.f) + kEps,
                         fmaxf(qv.z, 0.f) + kEps, fmaxf(qv.w, 0.f) + kEps};
#pragma unroll
    for (int dd = 0; dd < 4; ++dd) {
      const int d = 4 * d4 + dd;
      den = fmaf(qd[dd], Rb[KVSZ + d], den);
      const float* kvr = Rb + d * 64;          // uniform row -> SGPR broadcast
#pragma unroll
      for (int e = 0; e < 16; ++e) {
        acc[e].x = fmaf(qd[dd], kvr[4 * e + 0], acc[e].x);
        acc[e].y = fmaf(qd[dd], kvr[4 * e + 1], acc[e].y);
        acc[e].z = fmaf(qd[dd], kvr[4 * e + 2], acc[e].z);
        acc[e].w = fmaf(qd[dd], kvr[4 * e + 3], acc[e].w);
      }
    }
  }

  const float inv = 1.0f / den;
#pragma unroll
  for (int e = 0; e < 16; ++e) {
    acc[e].x *= inv; acc[e].y *= inv; acc[e].z *= inv; acc[e].w *= inv;
  }

  // staged coalesced store: batch bb covers 64 rows written by wave bb
  float* ob = out + ((size_t)bh * kS + (size_t)rowblk * 256) * kD;
  const int wid = tid >> 6, l = tid & 63;
  for (int bb = 0; bb < 4; ++bb) {
    if (wid == bb) {
#pragma unroll
      for (int e = 0; e < 16; ++e) *(float4*)&ost[l * 68 + 4 * e] = acc[e];
    }
    __syncthreads();
#pragma unroll
    for (int jj = 0; jj < 4; ++jj) {
      const int g = tid + 256 * jj;
      const int r = g >> 4, c = g & 15;
      *(float4*)&ob[(size_t)(bb * 64 + r) * kD + 4 * c] =
          *(const float4*)&ost[r * 68 + 4 * c];
    }
    __syncthreads();
  }
}

extern "C" void kernel_launch(void* const* d_in, const int* in_sizes, int n_in,
                              void* d_out, int out_size, void* d_ws, size_t ws_size,
                              hipStream_t stream) {
  const float* query = (const float*)d_in[0];
  const float* key   = (const float*)d_in[1];
  const float* value = (const float*)d_in[2];
  const float* mask  = (const float*)d_in[3];
  float* outp = (float*)d_out;

  // CH1 = S-chunks per bh; ONE segment per block. Pick largest that fits ws.
  auto need = [](int ch1) -> size_t {
    return (size_t)(kBH * ch1 + kBH) * SEG * sizeof(float);
  };
  int CH1 = 8;                                  // 9.2 MB, known-safe floor
  if (ws_size >= need(16)) CH1 = 16;            // 18.1 MB, 1024 blocks (4/CU)

  float* P = (float*)d_ws;                      // kBH*CH1 segments
  float* R = P + (size_t)kBH * CH1 * SEG;       // kBH segments (natural layout)

  hipLaunchKernelGGL(pa_kv_partial, dim3(kBH * CH1), dim3(256), 0, stream,
                     key, value, mask, P, CH1);
  hipLaunchKernelGGL(pa_reduce, dim3((kBH * F4PS + 255) / 256), dim3(256), 0, stream,
                     P, R, CH1);
  hipLaunchKernelGGL(pa_out, dim3(kBH * 16), dim3(256), 0, stream,
                     query, R, outp);
}